// Round 9
// baseline (312.018 us; speedup 1.0000x reference)
//
#include <hip/hip_runtime.h>
#include <math.h>

typedef unsigned int   uint;
typedef unsigned short ushort;

#define N_NODES 50000
#define DIM     128
#define N_EDGES 800000
#define N_UID   4096
#define LN_EPS  1e-5f
#define RST     132   // padded LDS row stride (floats)

typedef __attribute__((ext_vector_type(8))) short bf16x8;
typedef __attribute__((ext_vector_type(4))) float f32x4;
typedef __attribute__((ext_vector_type(4))) uint  u32x4;

// ---- bf16 helpers (storage only; math fp32) ----
__device__ __forceinline__ float bf_lo(uint u) { return __builtin_bit_cast(float, u << 16); }
__device__ __forceinline__ float bf_hi(uint u) { return __builtin_bit_cast(float, u & 0xffff0000u); }
__device__ __forceinline__ uint pack_bf16(float a, float b) {   // RNE
    uint ua = __builtin_bit_cast(uint, a);
    uint ub = __builtin_bit_cast(uint, b);
    uint ra = (ua + 0x7fffu + ((ua >> 16) & 1u)) >> 16;
    uint rb = (ub + 0x7fffu + ((ub >> 16) & 1u)) >> 16;
    return ra | (rb << 16);
}

// ---------- fused: emb->bf16, W->bf16, cnt=0 (one dispatch) ----------
__global__ __launch_bounds__(256) void cvtz_kernel(const float* __restrict__ emb, ushort* __restrict__ E,
                                                   const float* __restrict__ W, ushort* __restrict__ WB,
                                                   int* __restrict__ cnt) {
    int i = blockIdx.x * 256 + threadIdx.x;
    if (i < N_NODES * DIM / 4) {
        const float4 v = ((const float4*)emb)[i];
        uint2 p;
        p.x = pack_bf16(v.x, v.y);
        p.y = pack_bf16(v.z, v.w);
        ((uint2*)E)[i] = p;
    }
    if (i < 3 * DIM * DIM / 4) {
        const float4 v = ((const float4*)W)[i];
        uint2 p;
        p.x = pack_bf16(v.x, v.y);
        p.y = pack_bf16(v.z, v.w);
        ((uint2*)WB)[i] = p;
    }
    if (i < N_NODES) cnt[i] = 0;
}

// ---------- CSR build (1 edge/thread measured faster than 4/thread) ----------
__global__ __launch_bounds__(256) void deg_kernel(const int* __restrict__ dst, int* __restrict__ cnt) {
    int e = blockIdx.x * 256 + threadIdx.x;
    if (e < N_EDGES) atomicAdd(&cnt[dst[e]], 1);
}

__global__ __launch_bounds__(256) void scan1(const int* __restrict__ cnt, int* __restrict__ off,
                                             int* __restrict__ bsum) {
    __shared__ int sh[256];
    int t = threadIdx.x;
    int i = blockIdx.x * 256 + t;
    int v = (i < N_NODES) ? cnt[i] : 0;
    sh[t] = v;
    __syncthreads();
    for (int o = 1; o < 256; o <<= 1) {
        int x = (t >= o) ? sh[t - o] : 0;
        __syncthreads();
        sh[t] += x;
        __syncthreads();
    }
    if (i < N_NODES) off[i] = sh[t] - v;   // exclusive within block
    if (t == 255) bsum[blockIdx.x] = sh[255];
}

// fused scan2+scan3: every block redundantly scans the <=256 block sums in LDS
__global__ __launch_bounds__(256) void scan23(int* __restrict__ off, const int* __restrict__ bsum,
                                              int* __restrict__ cur, int nblk) {
    __shared__ int sh[256];
    int t = threadIdx.x;
    int v = (t < nblk) ? bsum[t] : 0;
    sh[t] = v;
    __syncthreads();
    for (int o = 1; o < 256; o <<= 1) {
        int x = (t >= o) ? sh[t - o] : 0;
        __syncthreads();
        sh[t] += x;
        __syncthreads();
    }
    const int pre = (blockIdx.x > 0) ? sh[blockIdx.x - 1] : 0;  // inclusive scan at blk-1
    int i = blockIdx.x * 256 + t;
    if (i < N_NODES) {
        int o = off[i] + pre;
        off[i] = o;
        cur[i] = o;
    }
    if (i == 0) off[N_NODES] = N_EDGES;
}

__global__ __launch_bounds__(256) void fill_kernel(const int* __restrict__ src, const int* __restrict__ dst,
                                                   int* __restrict__ cur, int* __restrict__ csr) {
    int e = blockIdx.x * 256 + threadIdx.x;
    if (e < N_EDGES) {
        int p = atomicAdd(&cur[dst[e]], 1);
        csr[p] = src[e];
    }
}

// ---------- aggregate: x_mean = (self + sum_neigh)/(deg+1), bf16 ----------
// 16-lane stream per TWO nodes (slot s and s+16), 32 nodes/block.
// Interleaved masked 8-row rounds: two independent gather chains per stream.
__global__ __launch_bounds__(256) void agg_kernel(
    const ushort* __restrict__ fin, ushort* __restrict__ xout,
    const int* __restrict__ off, const int* __restrict__ csr,
    const int* __restrict__ uidmap, int nslots)
{
    const int t  = threadIdx.x;
    const int lx = t & 15;                       // uint4 index within 256B row
    const int st = t >> 4;                       // stream 0..15
    const int slotA = blockIdx.x * 32 + st;
    const int slotB = slotA + 16;
    const bool vA = slotA < nslots;
    const bool vB = slotB < nslots;
    const int nA = vA ? (uidmap ? uidmap[slotA] : slotA) : 0;
    const int nB = vB ? (uidmap ? uidmap[slotB] : slotB) : 0;
    const int a0A = off[nA]; int a1A = off[nA + 1]; if (!vA) a1A = a0A;
    const int a0B = off[nB]; int a1B = off[nB + 1]; if (!vB) a1B = a0B;
    const int degA = a1A - a0A, degB = a1B - a0B;

    float2 A0, A1, A2, A3, B0, B1, B2, B3;
    {
        const uint4 sa = ((const uint4*)(fin + (size_t)nA * DIM))[lx];
        A0 = make_float2(bf_lo(sa.x), bf_hi(sa.x));
        A1 = make_float2(bf_lo(sa.y), bf_hi(sa.y));
        A2 = make_float2(bf_lo(sa.z), bf_hi(sa.z));
        A3 = make_float2(bf_lo(sa.w), bf_hi(sa.w));
        const uint4 sb = ((const uint4*)(fin + (size_t)nB * DIM))[lx];
        B0 = make_float2(bf_lo(sb.x), bf_hi(sb.x));
        B1 = make_float2(bf_lo(sb.y), bf_hi(sb.y));
        B2 = make_float2(bf_lo(sb.z), bf_hi(sb.z));
        B3 = make_float2(bf_lo(sb.w), bf_hi(sb.w));
    }

    int eA = a0A, eB = a0B;
    while (eA < a1A || eB < a1B) {
        const bool xA = eA < a1A;
        const bool xB = eB < a1B;
        int   idA[8], idB[8];
        float mA[8],  mB[8];
        if (xA) {
            const int lastA = a1A - 1;
            #pragma unroll
            for (int k = 0; k < 8; ++k) {
                const int ee = eA + k;
                idA[k] = csr[(ee <= lastA) ? ee : lastA];
                mA[k]  = (ee <= lastA) ? 1.0f : 0.0f;
            }
        }
        if (xB) {
            const int lastB = a1B - 1;
            #pragma unroll
            for (int k = 0; k < 8; ++k) {
                const int ee = eB + k;
                idB[k] = csr[(ee <= lastB) ? ee : lastB];
                mB[k]  = (ee <= lastB) ? 1.0f : 0.0f;
            }
        }
        uint4 va[8], vb[8];
        if (xA) {
            #pragma unroll
            for (int k = 0; k < 8; ++k)
                va[k] = ((const uint4*)(fin + (size_t)idA[k] * DIM))[lx];
        }
        if (xB) {
            #pragma unroll
            for (int k = 0; k < 8; ++k)
                vb[k] = ((const uint4*)(fin + (size_t)idB[k] * DIM))[lx];
        }
        if (xA) {
            #pragma unroll
            for (int k = 0; k < 8; ++k) {
                A0.x = fmaf(mA[k], bf_lo(va[k].x), A0.x); A0.y = fmaf(mA[k], bf_hi(va[k].x), A0.y);
                A1.x = fmaf(mA[k], bf_lo(va[k].y), A1.x); A1.y = fmaf(mA[k], bf_hi(va[k].y), A1.y);
                A2.x = fmaf(mA[k], bf_lo(va[k].z), A2.x); A2.y = fmaf(mA[k], bf_hi(va[k].z), A2.y);
                A3.x = fmaf(mA[k], bf_lo(va[k].w), A3.x); A3.y = fmaf(mA[k], bf_hi(va[k].w), A3.y);
            }
            eA += 8;
        }
        if (xB) {
            #pragma unroll
            for (int k = 0; k < 8; ++k) {
                B0.x = fmaf(mB[k], bf_lo(vb[k].x), B0.x); B0.y = fmaf(mB[k], bf_hi(vb[k].x), B0.y);
                B1.x = fmaf(mB[k], bf_lo(vb[k].y), B1.x); B1.y = fmaf(mB[k], bf_hi(vb[k].y), B1.y);
                B2.x = fmaf(mB[k], bf_lo(vb[k].z), B2.x); B2.y = fmaf(mB[k], bf_hi(vb[k].z), B2.y);
                B3.x = fmaf(mB[k], bf_lo(vb[k].w), B3.x); B3.y = fmaf(mB[k], bf_hi(vb[k].w), B3.y);
            }
            eB += 8;
        }
    }

    if (vA) {
        const float iv = 1.0f / (float)(degA + 1);
        uint4 p;
        p.x = pack_bf16(A0.x * iv, A0.y * iv);
        p.y = pack_bf16(A1.x * iv, A1.y * iv);
        p.z = pack_bf16(A2.x * iv, A2.y * iv);
        p.w = pack_bf16(A3.x * iv, A3.y * iv);
        ((uint4*)(xout + (size_t)slotA * DIM))[lx] = p;
    }
    if (vB) {
        const float iv = 1.0f / (float)(degB + 1);
        uint4 p;
        p.x = pack_bf16(B0.x * iv, B0.y * iv);
        p.y = pack_bf16(B1.x * iv, B1.y * iv);
        p.z = pack_bf16(B2.x * iv, B2.y * iv);
        p.w = pack_bf16(B3.x * iv, B3.y * iv);
        ((uint4*)(xout + (size_t)slotB * DIM))[lx] = p;
    }
}

// ---------- MFMA dense: y = x_mean @ W^T (+b), LN, ELU ----------
// block = 256 threads (4 waves), 32 rows × 128 cols of output.
// C/D: col = lane&15, row = (lane>>4)*4 + reg   [measured m89]
template <bool OUT_BF16>
__global__ __launch_bounds__(256) void mgemm_kernel(
    const ushort* __restrict__ xin, void* __restrict__ fout,
    const ushort* __restrict__ wb, const float* __restrict__ bias,
    const float* __restrict__ gamma, const float* __restrict__ beta, int nrows)
{
    __shared__ float ys[32 * RST];
    const int t    = threadIdx.x;
    const int wave = t >> 6, lane = t & 63;
    const int rows = blockIdx.x * 32;
    const int row_off = (wave >> 1) * 16;
    const int col_off = (wave & 1) * 64;
    const int lm   = lane & 15;
    const int quad = lane >> 4;

    f32x4 acc[4] = {f32x4{0,0,0,0}, f32x4{0,0,0,0}, f32x4{0,0,0,0}, f32x4{0,0,0,0}};
    const ushort* __restrict__ xrow = xin + (size_t)(rows + row_off + lm) * DIM + quad * 8;
    const ushort* __restrict__ wrow = wb  + (size_t)(col_off + lm) * DIM + quad * 8;
    #pragma unroll
    for (int kk = 0; kk < 4; ++kk) {
        const bf16x8 a = __builtin_bit_cast(bf16x8, *(const u32x4*)(xrow + kk * 32));
        #pragma unroll
        for (int c = 0; c < 4; ++c) {
            const bf16x8 b = __builtin_bit_cast(bf16x8,
                *(const u32x4*)(wrow + (size_t)c * 16 * DIM + kk * 32));
            acc[c] = __builtin_amdgcn_mfma_f32_16x16x32_bf16(a, b, acc[c], 0, 0, 0);
        }
    }

    #pragma unroll
    for (int c = 0; c < 4; ++c) {
        #pragma unroll
        for (int r = 0; r < 4; ++r)
            ys[(row_off + quad * 4 + r) * RST + col_off + c * 16 + lm] = acc[c][r];
    }
    __syncthreads();

    // LN + ELU: 8 threads per row, 16 dims each
    {
        const int r   = t >> 3;              // row 0..31
        const int seg = t & 7;               // 0..7
        const int db  = seg * 16;
        const float* yr = ys + r * RST + db;
        float vs[16];
        #pragma unroll
        for (int q = 0; q < 4; ++q) {
            const float4 y4 = ((const float4*)yr)[q];
            const float4 b4 = ((const float4*)(bias + db))[q];
            vs[q * 4 + 0] = y4.x + b4.x;
            vs[q * 4 + 1] = y4.y + b4.y;
            vs[q * 4 + 2] = y4.z + b4.z;
            vs[q * 4 + 3] = y4.w + b4.w;
        }
        float s1 = 0.0f, s2 = 0.0f;
        #pragma unroll
        for (int i = 0; i < 16; ++i) { s1 += vs[i]; s2 += vs[i] * vs[i]; }
        #pragma unroll
        for (int m = 1; m < 8; m <<= 1) {
            s1 += __shfl_xor(s1, m);
            s2 += __shfl_xor(s2, m);
        }
        const float mu  = s1 * (1.0f / 128.0f);
        const float var = s2 * (1.0f / 128.0f) - mu * mu;
        const float rs  = rsqrtf(var + LN_EPS);
        float ov[16];
        #pragma unroll
        for (int q = 0; q < 4; ++q) {
            const float4 g4 = ((const float4*)(gamma + db))[q];
            const float4 t4 = ((const float4*)(beta + db))[q];
            float z;
            z = (vs[q*4+0] - mu) * rs * g4.x + t4.x; ov[q*4+0] = (z > 0.0f) ? z : expm1f(z);
            z = (vs[q*4+1] - mu) * rs * g4.y + t4.y; ov[q*4+1] = (z > 0.0f) ? z : expm1f(z);
            z = (vs[q*4+2] - mu) * rs * g4.z + t4.z; ov[q*4+2] = (z > 0.0f) ? z : expm1f(z);
            z = (vs[q*4+3] - mu) * rs * g4.w + t4.w; ov[q*4+3] = (z > 0.0f) ? z : expm1f(z);
        }
        const int n = rows + r;
        if (n < nrows) {
            if (OUT_BF16) {
                uint4 p0, p1;
                p0.x = pack_bf16(ov[0],  ov[1]);  p0.y = pack_bf16(ov[2],  ov[3]);
                p0.z = pack_bf16(ov[4],  ov[5]);  p0.w = pack_bf16(ov[6],  ov[7]);
                p1.x = pack_bf16(ov[8],  ov[9]);  p1.y = pack_bf16(ov[10], ov[11]);
                p1.z = pack_bf16(ov[12], ov[13]); p1.w = pack_bf16(ov[14], ov[15]);
                uint4* op = (uint4*)((ushort*)fout + (size_t)n * DIM + db);
                op[0] = p0;
                op[1] = p1;
            } else {
                float* op = (float*)fout + (size_t)n * DIM + db;
                ((float4*)op)[0] = make_float4(ov[0],  ov[1],  ov[2],  ov[3]);
                ((float4*)op)[1] = make_float4(ov[4],  ov[5],  ov[6],  ov[7]);
                ((float4*)op)[2] = make_float4(ov[8],  ov[9],  ov[10], ov[11]);
                ((float4*)op)[3] = make_float4(ov[12], ov[13], ov[14], ov[15]);
            }
        }
    }
}

extern "C" void kernel_launch(void* const* d_in, const int* in_sizes, int n_in,
                              void* d_out, int out_size, void* d_ws, size_t ws_size,
                              hipStream_t stream) {
    const float* emb   = (const float*)d_in[0];
    const float* W     = (const float*)d_in[1];
    const float* bias  = (const float*)d_in[2];
    const float* gamma = (const float*)d_in[3];
    const float* beta  = (const float*)d_in[4];
    const int*   src   = (const int*)d_in[5];
    const int*   dst   = (const int*)d_in[6];
    const int*   uid   = (const int*)d_in[7];

    // workspace layout (~55 MB)
    ushort* E    = (ushort*)d_ws;                     // 50000*128 bf16 (embedding)
    ushort* X    = E + (size_t)N_NODES * DIM;         // (50000+64)*128 bf16 (x_mean, padded)
    ushort* A    = X + (size_t)(N_NODES + 64) * DIM;  // 50000*128 bf16
    ushort* B    = A + (size_t)N_NODES * DIM;         // 50000*128 bf16
    ushort* WB   = B + (size_t)N_NODES * DIM;         // 3*128*128 bf16
    int*    cnt  = (int*)(WB + 3 * DIM * DIM);        // 50000
    int*    off  = cnt + N_NODES;                     // 50001 (+pad)
    int*    cur  = off + (N_NODES + 4);               // 50000
    int*    bsum = cur + N_NODES;                     // 256
    int*    csr  = bsum + 256;                        // 800000

    const int eblk = (N_EDGES + 255) / 256;           // 3125
    const int nblk = (N_NODES + 255) / 256;           // 196
    cvtz_kernel<<<(N_NODES * DIM / 4 + 255) / 256, 256, 0, stream>>>(emb, E, W, WB, cnt);
    deg_kernel<<<eblk, 256, 0, stream>>>(dst, cnt);
    scan1<<<nblk, 256, 0, stream>>>(cnt, off, bsum);
    scan23<<<nblk, 256, 0, stream>>>(off, bsum, cur, nblk);
    fill_kernel<<<eblk, 256, 0, stream>>>(src, dst, cur, csr);

    const int ablk = (N_NODES + 31) / 32;             // 1563
    const int gblk = (N_NODES + 31) / 32;             // 1563
    // layer 1
    agg_kernel<<<ablk, 256, 0, stream>>>(E, X, off, csr, nullptr, N_NODES);
    mgemm_kernel<true><<<gblk, 256, 0, stream>>>(X, A, WB, bias, gamma, beta, N_NODES);
    // layer 2
    agg_kernel<<<ablk, 256, 0, stream>>>(A, X, off, csr, nullptr, N_NODES);
    mgemm_kernel<true><<<gblk, 256, 0, stream>>>(X, B, WB + DIM * DIM, bias + DIM,
                                                 gamma + DIM, beta + DIM, N_NODES);
    // layer 3: only uid nodes are read — aggregate + transform just those
    agg_kernel<<<N_UID / 32, 256, 0, stream>>>(B, X, off, csr, uid, N_UID);
    mgemm_kernel<false><<<N_UID / 32, 256, 0, stream>>>(X, (float*)d_out, WB + 2 * DIM * DIM,
                                                        bias + 2 * DIM, gamma + 2 * DIM,
                                                        beta + 2 * DIM, N_UID);
}